// Round 8
// baseline (81.058 us; speedup 1.0000x reference)
//
#include <hip/hip_runtime.h>

// GCNConv: out = D^-1/2 (A+I, dedup'd) D^-1/2 (X @ W)
// N=10000, IN_CH=256, OUT=256, E=320000
// R7: revert R6's divergent-__shfl gather (undefined for inactive source
//     lanes -> absmax 1.2) and 2-edge fill. Keep R5 structure; gather now
//     8 dual-loads in flight (direct col reads) + depth-4 mid stage.

#define CH 256
#define ELLW 96   // max raw row count; Poisson(32) => P(>=96) ~ 1e-19 per row

typedef __attribute__((ext_vector_type(8))) short short8;
typedef __attribute__((ext_vector_type(4))) float f32x4;

__device__ inline unsigned short f2b(float f) {   // fp32 -> bf16 RN-even
    unsigned x = __builtin_bit_cast(unsigned, f);
    x = (x + 0x7fffu + ((x >> 16) & 1u)) >> 16;
    return (unsigned short)x;
}
__device__ inline float b2f(unsigned short u) {
    unsigned v = ((unsigned)u) << 16;
    return __builtin_bit_cast(float, v);
}

__global__ void clear_cnt_kernel(int* cnt, int n) {
    int i = blockIdx.x * blockDim.x + threadIdx.x;
    if (i < n) cnt[i] = 0;
}

// Per-edge raw ELL fill (no dedup) + W^T -> bf16 conversion in the tail threads.
__global__ void fill_kernel(const int* __restrict__ ei, int e_cnt,
                            int* cnt, int* __restrict__ col_ell,
                            const float* __restrict__ w,
                            unsigned short* __restrict__ wt) {
    int t = blockIdx.x * blockDim.x + threadIdx.x;
    if (t < e_cnt) {
        int r = ei[t];
        int c = ei[e_cnt + t];
        int pos = atomicAdd(&cnt[r], 1);
        if (pos < ELLW) col_ell[(size_t)r * ELLW + pos] = c;
    } else if (t < e_cnt + CH * CH) {
        int idx = t - e_cnt;          // idx = k*CH + nn : coalesced read of w
        int k = idx >> 8, nn = idx & 255;
        wt[nn * CH + k] = f2b(w[idx]);
    }
}

// One wave per row: drop self-edges + duplicates, compact in place, deg[r]=m'+1.
// Rewrite col_ell only when something was dropped (~5% of rows).
__global__ __launch_bounds__(256) void dedup_kernel(
    int* cnt, int* __restrict__ col_ell, int* __restrict__ deg, int n) {
    __shared__ int sh[4][ELLW];
    const int wv = threadIdx.x >> 6, lane = threadIdx.x & 63;
    const int r = blockIdx.x * 4 + wv;

    int m = 0;
    if (r < n) { m = cnt[r]; if (m > ELLW) m = ELLW; }
    for (int e = lane; e < m; e += 64) sh[wv][e] = col_ell[(size_t)r * ELLW + e];
    __syncthreads();

    if (r < n) {
        const int e0 = lane, e1 = 64 + lane;
        int c0 = (e0 < m) ? sh[wv][e0] : -1;
        int c1 = (e1 < m) ? sh[wv][e1] : -1;
        bool dup0 = (c0 == r), dup1 = (c1 == r);
        for (int k = 0; k < m; ++k) {
            int ck = sh[wv][k];                 // uniform -> LDS broadcast
            dup0 |= (k < e0) && (ck == c0);
            dup1 |= (k < e1) && (ck == c1);
        }
        unsigned long long b0 = __ballot((e0 < m) && !dup0);
        unsigned long long b1 = __ballot((e1 < m) && !dup1);
        unsigned long long lt = (1ull << lane) - 1ull;
        int n0 = __popcll(b0);
        int mm = n0 + __popcll(b1);
        if (mm != m) {  // only rewrite rows that actually had drops
            if ((e0 < m) && !dup0)
                col_ell[(size_t)r * ELLW + __popcll(b0 & lt)] = c0;
            if ((e1 < m) && !dup1)
                col_ell[(size_t)r * ELLW + n0 + __popcll(b1 & lt)] = c1;
            if (lane == 0) cnt[r] = mm;
        }
        if (lane == 0) deg[r] = mm + 1;
    }
}

// Z = dinv[m] * (X @ W) in bf16. Block = 16 rows; wave wv owns cols [wv*64, wv*64+64).
__global__ __launch_bounds__(256) void gemm_kernel(
    const float* __restrict__ x, const unsigned short* __restrict__ wt,
    const int* __restrict__ deg, unsigned short* __restrict__ zb, int n) {
    const int tid = threadIdx.x;
    const int lane = tid & 63;
    const int wv = tid >> 6;
    const int m0 = blockIdx.x * 16;
    const int n0 = wv * 64;
    const int rsel = lane & 15;
    const int kbase = (lane >> 4) * 8;

    const float* xrow = x + (size_t)(m0 + rsel) * CH + kbase;
    const unsigned short* b0p = wt + (size_t)(n0 + rsel) * CH + kbase;
    const unsigned short* b1p = b0p + 16 * CH;
    const unsigned short* b2p = b0p + 32 * CH;
    const unsigned short* b3p = b0p + 48 * CH;

    f32x4 acc0 = {0.f, 0.f, 0.f, 0.f};
    f32x4 acc1 = acc0, acc2 = acc0, acc3 = acc0;

#pragma unroll
    for (int kc = 0; kc < 8; ++kc) {
        const float4* p = (const float4*)(xrow + kc * 32);
        float4 u = p[0], v = p[1];
        short8 a;
        a[0] = (short)f2b(u.x); a[1] = (short)f2b(u.y);
        a[2] = (short)f2b(u.z); a[3] = (short)f2b(u.w);
        a[4] = (short)f2b(v.x); a[5] = (short)f2b(v.y);
        a[6] = (short)f2b(v.z); a[7] = (short)f2b(v.w);
        short8 b0 = *(const short8*)(b0p + kc * 32);
        short8 b1 = *(const short8*)(b1p + kc * 32);
        short8 b2 = *(const short8*)(b2p + kc * 32);
        short8 b3 = *(const short8*)(b3p + kc * 32);
        acc0 = __builtin_amdgcn_mfma_f32_16x16x32_bf16(a, b0, acc0, 0, 0, 0);
        acc1 = __builtin_amdgcn_mfma_f32_16x16x32_bf16(a, b1, acc1, 0, 0, 0);
        acc2 = __builtin_amdgcn_mfma_f32_16x16x32_bf16(a, b2, acc2, 0, 0, 0);
        acc3 = __builtin_amdgcn_mfma_f32_16x16x32_bf16(a, b3, acc3, 0, 0, 0);
    }

    const int r0 = (lane >> 4) * 4;
    int4 dg = *(const int4*)(deg + m0 + r0);
    float dvj[4] = {rsqrtf((float)dg.x), rsqrtf((float)dg.y),
                    rsqrtf((float)dg.z), rsqrtf((float)dg.w)};
#pragma unroll
    for (int j = 0; j < 4; ++j) {
        unsigned short* zr = zb + (size_t)(m0 + r0 + j) * CH + n0 + rsel;
        zr[0]  = f2b(acc0[j] * dvj[j]);
        zr[16] = f2b(acc1[j] * dvj[j]);
        zr[32] = f2b(acc2[j] * dvj[j]);
        zr[48] = f2b(acc3[j] * dvj[j]);
    }
}

// One wave per row, dual-neighbor: 32 lanes cover one 512B Z row (ushort8 =
// 8 channels / lane); half 0 takes even neighbor slots, half 1 odd. Col
// indices read directly (L1-hot broadcast). 8 dual-loads in flight, then a
// depth-4 stage, then <=3 serial tail iterations.
__global__ __launch_bounds__(256) void gather_kernel(
    const int* __restrict__ cnt, const int* __restrict__ col_ell,
    const int* __restrict__ deg,
    const unsigned short* __restrict__ zb, float* __restrict__ out, int n) {
    int wid = (blockIdx.x * blockDim.x + threadIdx.x) >> 6;
    if (wid >= n) return;
    const int lane = threadIdx.x & 63;
    const int half = lane >> 5;       // 0: even neighbor slots, 1: odd
    const int chb = (lane & 31) * 8;  // this lane's 8 channels
    int m = cnt[wid]; if (m > ELLW) m = ELLW;
    const int* cl = col_ell + (size_t)wid * ELLW;
    const unsigned short* zc = zb + chb;

    float acc[8];
    if (half == 0) {  // self term added once
        short8 s = *(const short8*)(zc + (size_t)wid * CH);
#pragma unroll
        for (int i = 0; i < 8; ++i) acc[i] = b2f((unsigned short)s[i]);
    } else {
#pragma unroll
        for (int i = 0; i < 8; ++i) acc[i] = 0.f;
    }

    int idx = half;
    for (; idx + 14 < m; idx += 16) {  // 8 dual-loads in flight (16 slots)
        int c[8];
#pragma unroll
        for (int i = 0; i < 8; ++i) c[i] = cl[idx + 2 * i];
        short8 v[8];
#pragma unroll
        for (int i = 0; i < 8; ++i)
            v[i] = *(const short8*)(zc + (size_t)c[i] * CH);
#pragma unroll
        for (int i = 0; i < 8; ++i)
#pragma unroll
            for (int q = 0; q < 8; ++q)
                acc[q] += b2f((unsigned short)v[i][q]);
    }
    for (; idx + 6 < m; idx += 8) {    // depth-4 stage (8 slots)
        int c0 = cl[idx], c1 = cl[idx + 2], c2 = cl[idx + 4], c3 = cl[idx + 6];
        short8 v0 = *(const short8*)(zc + (size_t)c0 * CH);
        short8 v1 = *(const short8*)(zc + (size_t)c1 * CH);
        short8 v2 = *(const short8*)(zc + (size_t)c2 * CH);
        short8 v3 = *(const short8*)(zc + (size_t)c3 * CH);
#pragma unroll
        for (int q = 0; q < 8; ++q)
            acc[q] += b2f((unsigned short)v0[q]) + b2f((unsigned short)v1[q])
                    + b2f((unsigned short)v2[q]) + b2f((unsigned short)v3[q]);
    }
    for (; idx < m; idx += 2) {        // <=3 iterations
        int c = cl[idx];
        short8 v = *(const short8*)(zc + (size_t)c * CH);
#pragma unroll
        for (int q = 0; q < 8; ++q) acc[q] += b2f((unsigned short)v[q]);
    }

    // combine even/odd halves: lane L and L^32 own the same channels
#pragma unroll
    for (int i = 0; i < 8; ++i) acc[i] += __shfl_xor(acc[i], 32);

    float d = rsqrtf((float)deg[wid]);
    float4 o;
    if (half == 0) { o.x = acc[0]; o.y = acc[1]; o.z = acc[2]; o.w = acc[3]; }
    else           { o.x = acc[4]; o.y = acc[5]; o.z = acc[6]; o.w = acc[7]; }
    o.x *= d; o.y *= d; o.z *= d; o.w *= d;
    *(float4*)(out + (size_t)wid * CH + chb + half * 4) = o;
}

extern "C" void kernel_launch(void* const* d_in, const int* in_sizes, int n_in,
                              void* d_out, int out_size, void* d_ws, size_t ws_size,
                              hipStream_t stream) {
    const float* x = (const float*)d_in[0];
    const float* w = (const float*)d_in[1];
    const int* ei = (const int*)d_in[2];
    float* out = (float*)d_out;

    const int n = in_sizes[0] / CH;      // 10000
    const int e_cnt = in_sizes[2] / 2;   // 320000

    // workspace layout (all 16B-aligned)
    char* ws = (char*)d_ws;
    size_t off = 0;
    unsigned short* zb = (unsigned short*)(ws + off); off += (size_t)n * CH * 2;  // 5.12 MB
    unsigned short* wt = (unsigned short*)(ws + off); off += (size_t)CH * CH * 2; // 128 KB
    int* cnt = (int*)(ws + off);     off += (size_t)n * 4;                        // 40 KB
    int* deg = (int*)(ws + off);     off += (size_t)n * 4;                        // 40 KB
    int* col_ell = (int*)(ws + off); off += (size_t)n * ELLW * 4;                 // 3.84 MB

    clear_cnt_kernel<<<(n + 255) / 256, 256, 0, stream>>>(cnt, n);

    int total = e_cnt + CH * CH;
    fill_kernel<<<(total + 255) / 256, 256, 0, stream>>>(ei, e_cnt, cnt, col_ell, w, wt);
    dedup_kernel<<<(n + 3) / 4, 256, 0, stream>>>(cnt, col_ell, deg, n);
    gemm_kernel<<<n / 16, 256, 0, stream>>>(x, wt, deg, zb, n);
    gather_kernel<<<(n * 64 + 255) / 256, 256, 0, stream>>>(cnt, col_ell, deg, zb, out, n);
}

// Round 9
// 80.451 us; speedup vs baseline: 1.0075x; 1.0075x over previous
//
#include <hip/hip_runtime.h>

// GCNConv: out = D^-1/2 (A+I, dedup'd) D^-1/2 (X @ W)
// N=10000, IN_CH=256, OUT=256, E=320000
// R8: channel-sliced Z [2][N][128] so each gather slice's working set
//     (2.56 MB) is L2-resident per XCD (Z=5.12MB > 4MiB L2 was thrashing).
//     Quad-neighbor gather: 16 lanes/neighbor, 4 neighbors per wave-load.

#define CH 256
#define ELLW 96   // max raw row count; Poisson(32) => P(>=96) ~ 1e-19 per row

typedef __attribute__((ext_vector_type(8))) short short8;
typedef __attribute__((ext_vector_type(4))) float f32x4;

__device__ inline unsigned short f2b(float f) {   // fp32 -> bf16 RN-even
    unsigned x = __builtin_bit_cast(unsigned, f);
    x = (x + 0x7fffu + ((x >> 16) & 1u)) >> 16;
    return (unsigned short)x;
}
__device__ inline float b2f(unsigned short u) {
    unsigned v = ((unsigned)u) << 16;
    return __builtin_bit_cast(float, v);
}

__global__ void clear_cnt_kernel(int* cnt, int n) {
    int i = blockIdx.x * blockDim.x + threadIdx.x;
    if (i < n) cnt[i] = 0;
}

// Per-edge raw ELL fill (no dedup) + W^T -> bf16 conversion in the tail threads.
__global__ void fill_kernel(const int* __restrict__ ei, int e_cnt,
                            int* cnt, int* __restrict__ col_ell,
                            const float* __restrict__ w,
                            unsigned short* __restrict__ wt) {
    int t = blockIdx.x * blockDim.x + threadIdx.x;
    if (t < e_cnt) {
        int r = ei[t];
        int c = ei[e_cnt + t];
        int pos = atomicAdd(&cnt[r], 1);
        if (pos < ELLW) col_ell[(size_t)r * ELLW + pos] = c;
    } else if (t < e_cnt + CH * CH) {
        int idx = t - e_cnt;          // idx = k*CH + nn : coalesced read of w
        int k = idx >> 8, nn = idx & 255;
        wt[nn * CH + k] = f2b(w[idx]);
    }
}

// One wave per row: drop self-edges + duplicates, compact in place, deg[r]=m'+1.
// Rewrite col_ell only when something was dropped (~5% of rows).
__global__ __launch_bounds__(256) void dedup_kernel(
    int* cnt, int* __restrict__ col_ell, int* __restrict__ deg, int n) {
    __shared__ int sh[4][ELLW];
    const int wv = threadIdx.x >> 6, lane = threadIdx.x & 63;
    const int r = blockIdx.x * 4 + wv;

    int m = 0;
    if (r < n) { m = cnt[r]; if (m > ELLW) m = ELLW; }
    for (int e = lane; e < m; e += 64) sh[wv][e] = col_ell[(size_t)r * ELLW + e];
    __syncthreads();

    if (r < n) {
        const int e0 = lane, e1 = 64 + lane;
        int c0 = (e0 < m) ? sh[wv][e0] : -1;
        int c1 = (e1 < m) ? sh[wv][e1] : -1;
        bool dup0 = (c0 == r), dup1 = (c1 == r);
        for (int k = 0; k < m; ++k) {
            int ck = sh[wv][k];                 // uniform -> LDS broadcast
            dup0 |= (k < e0) && (ck == c0);
            dup1 |= (k < e1) && (ck == c1);
        }
        unsigned long long b0 = __ballot((e0 < m) && !dup0);
        unsigned long long b1 = __ballot((e1 < m) && !dup1);
        unsigned long long lt = (1ull << lane) - 1ull;
        int n0 = __popcll(b0);
        int mm = n0 + __popcll(b1);
        if (mm != m) {  // only rewrite rows that actually had drops
            if ((e0 < m) && !dup0)
                col_ell[(size_t)r * ELLW + __popcll(b0 & lt)] = c0;
            if ((e1 < m) && !dup1)
                col_ell[(size_t)r * ELLW + n0 + __popcll(b1 & lt)] = c1;
            if (lane == 0) cnt[r] = mm;
        }
        if (lane == 0) deg[r] = mm + 1;
    }
}

// Z = dinv[m] * (X @ W) in bf16, sliced layout zb[slice][row][128].
// Block = 16 rows; wave wv owns cols [wv*64, wv*64+64) -> slice = wv>>1.
__global__ __launch_bounds__(256) void gemm_kernel(
    const float* __restrict__ x, const unsigned short* __restrict__ wt,
    const int* __restrict__ deg, unsigned short* __restrict__ zb, int n) {
    const int tid = threadIdx.x;
    const int lane = tid & 63;
    const int wv = tid >> 6;
    const int m0 = blockIdx.x * 16;
    const int n0 = wv * 64;
    const int rsel = lane & 15;
    const int kbase = (lane >> 4) * 8;

    const float* xrow = x + (size_t)(m0 + rsel) * CH + kbase;
    const unsigned short* b0p = wt + (size_t)(n0 + rsel) * CH + kbase;
    const unsigned short* b1p = b0p + 16 * CH;
    const unsigned short* b2p = b0p + 32 * CH;
    const unsigned short* b3p = b0p + 48 * CH;

    f32x4 acc0 = {0.f, 0.f, 0.f, 0.f};
    f32x4 acc1 = acc0, acc2 = acc0, acc3 = acc0;

#pragma unroll
    for (int kc = 0; kc < 8; ++kc) {
        const float4* p = (const float4*)(xrow + kc * 32);
        float4 u = p[0], v = p[1];
        short8 a;
        a[0] = (short)f2b(u.x); a[1] = (short)f2b(u.y);
        a[2] = (short)f2b(u.z); a[3] = (short)f2b(u.w);
        a[4] = (short)f2b(v.x); a[5] = (short)f2b(v.y);
        a[6] = (short)f2b(v.z); a[7] = (short)f2b(v.w);
        short8 b0 = *(const short8*)(b0p + kc * 32);
        short8 b1 = *(const short8*)(b1p + kc * 32);
        short8 b2 = *(const short8*)(b2p + kc * 32);
        short8 b3 = *(const short8*)(b3p + kc * 32);
        acc0 = __builtin_amdgcn_mfma_f32_16x16x32_bf16(a, b0, acc0, 0, 0, 0);
        acc1 = __builtin_amdgcn_mfma_f32_16x16x32_bf16(a, b1, acc1, 0, 0, 0);
        acc2 = __builtin_amdgcn_mfma_f32_16x16x32_bf16(a, b2, acc2, 0, 0, 0);
        acc3 = __builtin_amdgcn_mfma_f32_16x16x32_bf16(a, b3, acc3, 0, 0, 0);
    }

    const int r0 = (lane >> 4) * 4;
    int4 dg = *(const int4*)(deg + m0 + r0);
    float dvj[4] = {rsqrtf((float)dg.x), rsqrtf((float)dg.y),
                    rsqrtf((float)dg.z), rsqrtf((float)dg.w)};
    const int slice = n0 >> 7;     // waves 0,1 -> slice 0; 2,3 -> slice 1
    const int nn0 = n0 & 127;
#pragma unroll
    for (int j = 0; j < 4; ++j) {
        unsigned short* zr = zb + ((size_t)slice * n + (m0 + r0 + j)) * 128 + nn0 + rsel;
        zr[0]  = f2b(acc0[j] * dvj[j]);
        zr[16] = f2b(acc1[j] * dvj[j]);
        zr[32] = f2b(acc2[j] * dvj[j]);
        zr[48] = f2b(acc3[j] * dvj[j]);
    }
}

// One wave per (slice,row): 16 lanes cover one 256B Z-slice row; lane group
// g=lane>>4 takes neighbor slots g, g+4, ... (per-group uniform cl[] broadcast
// loads; no shfl in loop). 4 quad-loads in flight; groups combine after the
// loop via shfl_xor(16/32). Blocks 0..2499 = slice 0, 2500..4999 = slice 1
// -> per-XCD L2 working set 2.56 MB (fits 4 MiB).
__global__ __launch_bounds__(256) void gather_kernel(
    const int* __restrict__ cnt, const int* __restrict__ col_ell,
    const int* __restrict__ deg,
    const unsigned short* __restrict__ zb, float* __restrict__ out, int n) {
    int wgid = (blockIdx.x * blockDim.x + threadIdx.x) >> 6;
    if (wgid >= 2 * n) return;
    const int slice = (wgid >= n) ? 1 : 0;
    const int wid = wgid - slice * n;
    const int lane = threadIdx.x & 63;
    const int g = lane >> 4;          // neighbor phase 0..3
    const int chb = (lane & 15) * 8;  // 8 channels within the 128-ch slice
    int m = cnt[wid]; if (m > ELLW) m = ELLW;
    const int* cl = col_ell + (size_t)wid * ELLW;
    const unsigned short* zs = zb + (size_t)slice * n * 128 + chb;

    float acc[8];
    if (g == 0) {  // self term added once
        short8 s = *(const short8*)(zs + (size_t)wid * 128);
#pragma unroll
        for (int i = 0; i < 8; ++i) acc[i] = b2f((unsigned short)s[i]);
    } else {
#pragma unroll
        for (int i = 0; i < 8; ++i) acc[i] = 0.f;
    }

    int idx = g;
    for (; idx + 12 < m; idx += 16) {  // 4 quad-loads in flight (16 slots)
        int c0 = cl[idx], c1 = cl[idx + 4], c2 = cl[idx + 8], c3 = cl[idx + 12];
        short8 v0 = *(const short8*)(zs + (size_t)c0 * 128);
        short8 v1 = *(const short8*)(zs + (size_t)c1 * 128);
        short8 v2 = *(const short8*)(zs + (size_t)c2 * 128);
        short8 v3 = *(const short8*)(zs + (size_t)c3 * 128);
#pragma unroll
        for (int q = 0; q < 8; ++q)
            acc[q] += b2f((unsigned short)v0[q]) + b2f((unsigned short)v1[q])
                    + b2f((unsigned short)v2[q]) + b2f((unsigned short)v3[q]);
    }
    for (; idx < m; idx += 4) {        // <=3 iterations
        int c = cl[idx];
        short8 v = *(const short8*)(zs + (size_t)c * 128);
#pragma unroll
        for (int q = 0; q < 8; ++q) acc[q] += b2f((unsigned short)v[q]);
    }

    // combine the 4 lane groups (lanes L, L^16, L^32, L^48 share channels)
#pragma unroll
    for (int i = 0; i < 8; ++i) acc[i] += __shfl_xor(acc[i], 16);
#pragma unroll
    for (int i = 0; i < 8; ++i) acc[i] += __shfl_xor(acc[i], 32);

    if (g == 0) {
        float d = rsqrtf((float)deg[wid]);
        float* dst = out + (size_t)wid * CH + slice * 128 + chb;
        float4 o0, o1;
        o0.x = acc[0] * d; o0.y = acc[1] * d; o0.z = acc[2] * d; o0.w = acc[3] * d;
        o1.x = acc[4] * d; o1.y = acc[5] * d; o1.z = acc[6] * d; o1.w = acc[7] * d;
        *(float4*)dst = o0;
        *(float4*)(dst + 4) = o1;
    }
}

extern "C" void kernel_launch(void* const* d_in, const int* in_sizes, int n_in,
                              void* d_out, int out_size, void* d_ws, size_t ws_size,
                              hipStream_t stream) {
    const float* x = (const float*)d_in[0];
    const float* w = (const float*)d_in[1];
    const int* ei = (const int*)d_in[2];
    float* out = (float*)d_out;

    const int n = in_sizes[0] / CH;      // 10000
    const int e_cnt = in_sizes[2] / 2;   // 320000

    // workspace layout (all 16B-aligned)
    char* ws = (char*)d_ws;
    size_t off = 0;
    unsigned short* zb = (unsigned short*)(ws + off); off += (size_t)n * CH * 2;  // 5.12 MB
    unsigned short* wt = (unsigned short*)(ws + off); off += (size_t)CH * CH * 2; // 128 KB
    int* cnt = (int*)(ws + off);     off += (size_t)n * 4;                        // 40 KB
    int* deg = (int*)(ws + off);     off += (size_t)n * 4;                        // 40 KB
    int* col_ell = (int*)(ws + off); off += (size_t)n * ELLW * 4;                 // 3.84 MB

    clear_cnt_kernel<<<(n + 255) / 256, 256, 0, stream>>>(cnt, n);

    int total = e_cnt + CH * CH;
    fill_kernel<<<(total + 255) / 256, 256, 0, stream>>>(ei, e_cnt, cnt, col_ell, w, wt);
    dedup_kernel<<<(n + 3) / 4, 256, 0, stream>>>(cnt, col_ell, deg, n);
    gemm_kernel<<<n / 16, 256, 0, stream>>>(x, wt, deg, zb, n);
    gather_kernel<<<(2 * n * 64 + 255) / 256, 256, 0, stream>>>(cnt, col_ell, deg, zb, out, n);
}

// Round 10
// 77.123 us; speedup vs baseline: 1.0510x; 1.0432x over previous
//
#include <hip/hip_runtime.h>

// GCNConv: out = D^-1/2 (A+I, dedup'd) D^-1/2 (X @ W)
// N=10000, IN_CH=256, OUT=256, E=320000
// R9: restructure the serial chain. Z stores unscaled Y (gather applies
//     dinv[c] via FMA) -> gemm independent of graph; fill+gemm fused as
//     disjoint block ranges; clear+Wt fused; gather slice = blockIdx&1
//     (XCD-parity locality). 4 dispatches: prep -> fill|gemm -> dedup -> gather.

#define CH 256
#define ELLW 96   // max raw row count; Poisson(32) => P(>=96) ~ 1e-19 per row

typedef __attribute__((ext_vector_type(8))) short short8;
typedef __attribute__((ext_vector_type(4))) float f32x4;

__device__ inline unsigned short f2b(float f) {   // fp32 -> bf16 RN-even
    unsigned x = __builtin_bit_cast(unsigned, f);
    x = (x + 0x7fffu + ((x >> 16) & 1u)) >> 16;
    return (unsigned short)x;
}
__device__ inline float b2f(unsigned short u) {
    unsigned v = ((unsigned)u) << 16;
    return __builtin_bit_cast(float, v);
}

// K1: clear cnt + W^T -> bf16.
__global__ void prep_kernel(int* cnt, int n, const float* __restrict__ w,
                            unsigned short* __restrict__ wt) {
    int t = blockIdx.x * blockDim.x + threadIdx.x;
    if (t < n) {
        cnt[t] = 0;
    } else if (t < n + CH * CH) {
        int idx = t - n;              // idx = k*CH + nn : coalesced read of w
        int k = idx >> 8, nn = idx & 255;
        wt[nn * CH + k] = f2b(w[idx]);
    }
}

// K2: blocks [0,fillb) do per-edge raw ELL fill; blocks [fillb, fillb+n/16)
// do the MFMA GEMM (Z = X@W unscaled, bf16, sliced layout [2][n][128]).
// The two halves are independent and co-resident -> gemm hides under fill.
__global__ __launch_bounds__(256) void fillgemm_kernel(
    const int* __restrict__ ei, int e_cnt, int* cnt, int* __restrict__ col_ell,
    const float* __restrict__ x, const unsigned short* __restrict__ wt,
    unsigned short* __restrict__ zb, int n, int fillb) {
    if ((int)blockIdx.x < fillb) {
        int e = blockIdx.x * blockDim.x + threadIdx.x;
        if (e < e_cnt) {
            int r = ei[e];
            int c = ei[e_cnt + e];
            int pos = atomicAdd(&cnt[r], 1);
            if (pos < ELLW) col_ell[(size_t)r * ELLW + pos] = c;
        }
        return;
    }
    const int blk = blockIdx.x - fillb;
    const int tid = threadIdx.x;
    const int lane = tid & 63;
    const int wv = tid >> 6;
    const int m0 = blk * 16;
    const int n0 = wv * 64;
    const int rsel = lane & 15;
    const int kbase = (lane >> 4) * 8;

    const float* xrow = x + (size_t)(m0 + rsel) * CH + kbase;
    const unsigned short* b0p = wt + (size_t)(n0 + rsel) * CH + kbase;
    const unsigned short* b1p = b0p + 16 * CH;
    const unsigned short* b2p = b0p + 32 * CH;
    const unsigned short* b3p = b0p + 48 * CH;

    f32x4 acc0 = {0.f, 0.f, 0.f, 0.f};
    f32x4 acc1 = acc0, acc2 = acc0, acc3 = acc0;

#pragma unroll
    for (int kc = 0; kc < 8; ++kc) {
        const float4* p = (const float4*)(xrow + kc * 32);
        float4 u = p[0], v = p[1];
        short8 a;
        a[0] = (short)f2b(u.x); a[1] = (short)f2b(u.y);
        a[2] = (short)f2b(u.z); a[3] = (short)f2b(u.w);
        a[4] = (short)f2b(v.x); a[5] = (short)f2b(v.y);
        a[6] = (short)f2b(v.z); a[7] = (short)f2b(v.w);
        short8 b0 = *(const short8*)(b0p + kc * 32);
        short8 b1 = *(const short8*)(b1p + kc * 32);
        short8 b2 = *(const short8*)(b2p + kc * 32);
        short8 b3 = *(const short8*)(b3p + kc * 32);
        acc0 = __builtin_amdgcn_mfma_f32_16x16x32_bf16(a, b0, acc0, 0, 0, 0);
        acc1 = __builtin_amdgcn_mfma_f32_16x16x32_bf16(a, b1, acc1, 0, 0, 0);
        acc2 = __builtin_amdgcn_mfma_f32_16x16x32_bf16(a, b2, acc2, 0, 0, 0);
        acc3 = __builtin_amdgcn_mfma_f32_16x16x32_bf16(a, b3, acc3, 0, 0, 0);
    }

    const int r0 = (lane >> 4) * 4;
    const int slice = n0 >> 7;     // waves 0,1 -> slice 0; 2,3 -> slice 1
    const int nn0 = n0 & 127;
#pragma unroll
    for (int j = 0; j < 4; ++j) {
        unsigned short* zr = zb + ((size_t)slice * n + (m0 + r0 + j)) * 128 + nn0 + rsel;
        zr[0]  = f2b(acc0[j]);
        zr[16] = f2b(acc1[j]);
        zr[32] = f2b(acc2[j]);
        zr[48] = f2b(acc3[j]);
    }
}

// K3: one wave per row: drop self-edges + duplicates, compact in place,
// write dinv[r] = rsqrt(m'+1). Rewrite col_ell only when something dropped.
__global__ __launch_bounds__(256) void dedup_kernel(
    int* cnt, int* __restrict__ col_ell, float* __restrict__ dinv, int n) {
    __shared__ int sh[4][ELLW];
    const int wv = threadIdx.x >> 6, lane = threadIdx.x & 63;
    const int r = blockIdx.x * 4 + wv;

    int m = 0;
    if (r < n) { m = cnt[r]; if (m > ELLW) m = ELLW; }
    for (int e = lane; e < m; e += 64) sh[wv][e] = col_ell[(size_t)r * ELLW + e];
    __syncthreads();

    if (r < n) {
        const int e0 = lane, e1 = 64 + lane;
        int c0 = (e0 < m) ? sh[wv][e0] : -1;
        int c1 = (e1 < m) ? sh[wv][e1] : -1;
        bool dup0 = (c0 == r), dup1 = (c1 == r);
        for (int k = 0; k < m; ++k) {
            int ck = sh[wv][k];                 // uniform -> LDS broadcast
            dup0 |= (k < e0) && (ck == c0);
            dup1 |= (k < e1) && (ck == c1);
        }
        unsigned long long b0 = __ballot((e0 < m) && !dup0);
        unsigned long long b1 = __ballot((e1 < m) && !dup1);
        unsigned long long lt = (1ull << lane) - 1ull;
        int n0 = __popcll(b0);
        int mm = n0 + __popcll(b1);
        if (mm != m) {  // only rewrite rows that actually had drops
            if ((e0 < m) && !dup0)
                col_ell[(size_t)r * ELLW + __popcll(b0 & lt)] = c0;
            if ((e1 < m) && !dup1)
                col_ell[(size_t)r * ELLW + n0 + __popcll(b1 & lt)] = c1;
            if (lane == 0) cnt[r] = mm;
        }
        if (lane == 0) dinv[r] = rsqrtf((float)(mm + 1));
    }
}

// K4: gather. Block b: slice = b&1 (if block->XCD is b%8, even XCDs see only
// slice 0 -> 2.56 MB L2-resident), rows (b>>1)*4 + wave. Lane group g=lane>>4
// handles neighbor slots g, g+4,... (16 lanes x 16B = one 256B slice row).
// acc += dinv[c] * Y[c]; final out = dinv[r] * acc. 4 quad-loads in flight.
__global__ __launch_bounds__(256) void gather_kernel(
    const int* __restrict__ cnt, const int* __restrict__ col_ell,
    const float* __restrict__ dinv,
    const unsigned short* __restrict__ zb, float* __restrict__ out, int n) {
    const int b = blockIdx.x;
    const int slice = b & 1;
    const int wv = threadIdx.x >> 6;
    const int wid = (b >> 1) * 4 + wv;
    if (wid >= n) return;
    const int lane = threadIdx.x & 63;
    const int g = lane >> 4;          // neighbor phase 0..3
    const int chb = (lane & 15) * 8;  // 8 channels within the 128-ch slice
    int m = cnt[wid]; if (m > ELLW) m = ELLW;
    const int* cl = col_ell + (size_t)wid * ELLW;
    const unsigned short* zs = zb + (size_t)slice * n * 128 + chb;
    const float dr = dinv[wid];

    float acc[8];
    if (g == 0) {  // self term: dinv[r] * Y[r]
        short8 s = *(const short8*)(zs + (size_t)wid * 128);
#pragma unroll
        for (int q = 0; q < 8; ++q) acc[q] = dr * b2f((unsigned short)s[q]);
    } else {
#pragma unroll
        for (int q = 0; q < 8; ++q) acc[q] = 0.f;
    }

    int idx = g;
    for (; idx + 12 < m; idx += 16) {  // 4 quad-loads in flight (16 slots)
        int c0 = cl[idx], c1 = cl[idx + 4], c2 = cl[idx + 8], c3 = cl[idx + 12];
        float d0 = dinv[c0], d1 = dinv[c1], d2 = dinv[c2], d3 = dinv[c3];
        short8 v0 = *(const short8*)(zs + (size_t)c0 * 128);
        short8 v1 = *(const short8*)(zs + (size_t)c1 * 128);
        short8 v2 = *(const short8*)(zs + (size_t)c2 * 128);
        short8 v3 = *(const short8*)(zs + (size_t)c3 * 128);
#pragma unroll
        for (int q = 0; q < 8; ++q)
            acc[q] += d0 * b2f((unsigned short)v0[q]) + d1 * b2f((unsigned short)v1[q])
                    + d2 * b2f((unsigned short)v2[q]) + d3 * b2f((unsigned short)v3[q]);
    }
    for (; idx < m; idx += 4) {        // <=3 iterations
        int c = cl[idx];
        float dc = dinv[c];
        short8 v = *(const short8*)(zs + (size_t)c * 128);
#pragma unroll
        for (int q = 0; q < 8; ++q) acc[q] += dc * b2f((unsigned short)v[q]);
    }

    // combine the 4 lane groups (lanes L, L^16, L^32, L^48 share channels)
#pragma unroll
    for (int q = 0; q < 8; ++q) acc[q] += __shfl_xor(acc[q], 16);
#pragma unroll
    for (int q = 0; q < 8; ++q) acc[q] += __shfl_xor(acc[q], 32);

    if (g == 0) {
        float* dst = out + (size_t)wid * CH + slice * 128 + chb;
        float4 o0, o1;
        o0.x = acc[0] * dr; o0.y = acc[1] * dr; o0.z = acc[2] * dr; o0.w = acc[3] * dr;
        o1.x = acc[4] * dr; o1.y = acc[5] * dr; o1.z = acc[6] * dr; o1.w = acc[7] * dr;
        *(float4*)dst = o0;
        *(float4*)(dst + 4) = o1;
    }
}

extern "C" void kernel_launch(void* const* d_in, const int* in_sizes, int n_in,
                              void* d_out, int out_size, void* d_ws, size_t ws_size,
                              hipStream_t stream) {
    const float* x = (const float*)d_in[0];
    const float* w = (const float*)d_in[1];
    const int* ei = (const int*)d_in[2];
    float* out = (float*)d_out;

    const int n = in_sizes[0] / CH;      // 10000
    const int e_cnt = in_sizes[2] / 2;   // 320000

    // workspace layout (all 16B-aligned)
    char* ws = (char*)d_ws;
    size_t off = 0;
    unsigned short* zb = (unsigned short*)(ws + off); off += (size_t)n * CH * 2;  // 5.12 MB
    unsigned short* wt = (unsigned short*)(ws + off); off += (size_t)CH * CH * 2; // 128 KB
    int* cnt = (int*)(ws + off);      off += (size_t)n * 4;                       // 40 KB
    float* dinv = (float*)(ws + off); off += (size_t)n * 4;                       // 40 KB
    int* col_ell = (int*)(ws + off);  off += (size_t)n * ELLW * 4;                // 3.84 MB

    // K1: clear cnt + convert W^T
    prep_kernel<<<(n + CH * CH + 255) / 256, 256, 0, stream>>>(cnt, n, w, wt);

    // K2: fill (1250 blocks) || gemm (625 blocks)
    const int fillb = (e_cnt + 255) / 256;
    fillgemm_kernel<<<fillb + n / 16, 256, 0, stream>>>(ei, e_cnt, cnt, col_ell,
                                                        x, wt, zb, n, fillb);

    // K3: dedup + dinv
    dedup_kernel<<<(n + 3) / 4, 256, 0, stream>>>(cnt, col_ell, dinv, n);

    // K4: gather (2 slices x n rows, 4 rows/block)
    gather_kernel<<<2 * ((n + 3) / 4), 256, 0, stream>>>(cnt, col_ell, dinv, zb, out, n);
}